// Round 4
// baseline (100.940 us; speedup 1.0000x reference)
//
#include <hip/hip_runtime.h>
#include <hip/hip_bf16.h>
#include <stdint.h>
#include <stddef.h>

typedef __bf16 bf16_t;
typedef __attribute__((ext_vector_type(8))) __bf16 bf16x8;
typedef __attribute__((ext_vector_type(4))) float f32x4;

#define TOK 2048      // N*M tokens
#define DMODEL 1024
#define NHEAD 16

__device__ __forceinline__ void gload_lds16(const void* g, void* l) {
  __builtin_amdgcn_global_load_lds(
      (const __attribute__((address_space(1))) void*)g,
      (__attribute__((address_space(3))) void*)l, 16, 0, 0);
}

// ---------------- fp32 -> bf16 convert (weights only) ----------------
struct CvtArgs {
  const float* src[4];
  bf16_t* dst[4];
};

__global__ __launch_bounds__(256) void cvt_kernel(CvtArgs a) {
  int arr = blockIdx.y;
  int i = (blockIdx.x * 256 + threadIdx.x) * 8;
  const float* s = a.src[arr];
  bf16_t* d = a.dst[arr];
  f32x4 x0 = *(const f32x4*)(s + i);
  f32x4 x1 = *(const f32x4*)(s + i + 4);
  bf16x8 o;
  o[0] = (bf16_t)x0[0]; o[1] = (bf16_t)x0[1]; o[2] = (bf16_t)x0[2]; o[3] = (bf16_t)x0[3];
  o[4] = (bf16_t)x1[0]; o[5] = (bf16_t)x1[1]; o[6] = (bf16_t)x1[2]; o[7] = (bf16_t)x1[3];
  *(bf16x8*)(d + i) = o;
}

// =============== 64x64-tile GEMM, BK=64, 2-phase dbuf pipeline ===============
// C[row][col] = sum_k A[row][k] * W[col][k] + bias[col]
// AF32: A is fp32, reg-staged (fp32->bf16 cvt in flight) into padded LDS.
// else: A is bf16, staged via global_load_lds into linear XOR-swizzled LDS.
// W always staged via global_load_lds (linear, XOR chunk swizzle both sides).
struct GArgs {
  const void* A[3];
  const bf16_t* W[3];
  const float* bias[3];
  void* C[3];
};

template <bool AF32, typename CT>
__global__ __launch_bounds__(256, 4) void gemm3(GArgs g, int K) {
  const int z = blockIdx.z;
  const bf16_t* __restrict__ W = g.W[z];
  const float* __restrict__ bias = g.bias[z];
  CT* __restrict__ C = (CT*)g.C[z];

  // bijective XCD swizzle (nwg multiple of 8)
  const int gx = gridDim.x;
  const int nwg = gx * gridDim.y;
  const int oldid = blockIdx.x + gx * blockIdx.y;
  const int nid = (oldid & 7) * (nwg >> 3) + (oldid >> 3);
  const int bm = (nid % gx) * 64;
  const int bn = (nid / gx) * 64;
  const int N = gridDim.y * 64;

  constexpr int ALD = AF32 ? 72 : 64;          // A row stride (elems)
  __shared__ alignas(16) bf16_t As[2][64 * ALD];
  __shared__ alignas(16) bf16_t Bs[2][64 * 64];

  const int tid = threadIdx.x;
  const int wv = tid >> 6, lane = tid & 63;
  const int wr = (wv >> 1) * 32, wc = (wv & 1) * 32;
  const int lm = lane & 15, lch = lane >> 4;    // frag row sel, k-chunk sel
  const int cr4 = (lane >> 4) * 4;

  // gload_lds staging coords: wave covers 8 rows per instr, lane -> row srow, chunk sc
  const int srow = wv * 8 + (lane >> 3);
  const int sc = (lane & 7) ^ (lane >> 3);      // inverse-swizzled source chunk
  const bf16_t* Wbase = W + (size_t)(bn + srow) * K + sc * 8;

  // A fp32 reg-staging coords (AF32 path)
  const int trow = tid >> 2, tcol = (tid & 3) * 16;
  const float* Af = AF32 ? ((const float*)g.A[z] + (size_t)(bm + trow) * K + tcol) : nullptr;
  const bf16_t* Abase = AF32 ? nullptr
                             : ((const bf16_t*)g.A[z] + (size_t)(bm + srow) * K + sc * 8);

  f32x4 acc[2][2] = {};
  const int nt = K / 64;

  // ---- prologue: stage tile 0 into buf 0 ----
  {
    gload_lds16(Wbase, &Bs[0][(wv * 8) * 64]);
    gload_lds16(Wbase + (size_t)32 * K, &Bs[0][(wv * 8 + 32) * 64]);
    if (!AF32) {
      gload_lds16(Abase, &As[0][(wv * 8) * 64]);
      gload_lds16(Abase + (size_t)32 * K, &As[0][(wv * 8 + 32) * 64]);
    } else {
      f32x4 a0 = *(const f32x4*)(Af);
      f32x4 a1 = *(const f32x4*)(Af + 4);
      f32x4 a2 = *(const f32x4*)(Af + 8);
      f32x4 a3 = *(const f32x4*)(Af + 12);
      bf16x8 c0, c1;
#pragma unroll
      for (int e = 0; e < 4; ++e) {
        c0[e] = (bf16_t)a0[e]; c0[e + 4] = (bf16_t)a1[e];
        c1[e] = (bf16_t)a2[e]; c1[e + 4] = (bf16_t)a3[e];
      }
      *(bf16x8*)&As[0][trow * ALD + tcol] = c0;
      *(bf16x8*)&As[0][trow * ALD + tcol + 8] = c1;
    }
  }
  asm volatile("s_waitcnt vmcnt(0) lgkmcnt(0)" ::: "memory");
  __builtin_amdgcn_sched_barrier(0);
  __builtin_amdgcn_s_barrier();

  int cur = 0;
  for (int t = 0; t < nt; ++t) {
    const bool more = (t + 1) < nt;
    // ---- issue stage of tile t+1 into buf cur^1 (no wait) ----
    f32x4 na0, na1, na2, na3;
    if (more) {
      const bf16_t* wsrc = Wbase + (size_t)(t + 1) * 64;
      gload_lds16(wsrc, &Bs[cur ^ 1][(wv * 8) * 64]);
      gload_lds16(wsrc + (size_t)32 * K, &Bs[cur ^ 1][(wv * 8 + 32) * 64]);
      if (!AF32) {
        const bf16_t* asrc = Abase + (size_t)(t + 1) * 64;
        gload_lds16(asrc, &As[cur ^ 1][(wv * 8) * 64]);
        gload_lds16(asrc + (size_t)32 * K, &As[cur ^ 1][(wv * 8 + 32) * 64]);
      } else {
        const float* ap = Af + (size_t)(t + 1) * 64;
        na0 = *(const f32x4*)(ap);
        na1 = *(const f32x4*)(ap + 4);
        na2 = *(const f32x4*)(ap + 8);
        na3 = *(const f32x4*)(ap + 12);
      }
    }

    // ---- read fragments of tile t from buf cur ----
    bf16x8 fa[2][2], fb[2][2];
#pragma unroll
    for (int kk = 0; kk < 2; ++kk)
#pragma unroll
      for (int i = 0; i < 2; ++i) {
        const int ra = wr + i * 16 + lm;
        if (AF32) {
          fa[kk][i] = *(const bf16x8*)&As[cur][ra * ALD + kk * 32 + lch * 8];
        } else {
          fa[kk][i] = *(const bf16x8*)&As[cur][ra * 64 + (((kk * 4 + lch) ^ (ra & 7)) * 8)];
        }
        const int rb = wc + i * 16 + lm;
        fb[kk][i] = *(const bf16x8*)&Bs[cur][rb * 64 + (((kk * 4 + lch) ^ (rb & 7)) * 8)];
      }

    // ---- MFMA ----
#pragma unroll
    for (int kk = 0; kk < 2; ++kk)
#pragma unroll
      for (int i = 0; i < 2; ++i)
#pragma unroll
        for (int j = 0; j < 2; ++j)
          acc[i][j] = __builtin_amdgcn_mfma_f32_16x16x32_bf16(fa[kk][i], fb[kk][j], acc[i][j], 0, 0, 0);

    // ---- AF32: convert prefetched A regs, write to buf cur^1 ----
    if (AF32 && more) {
      bf16x8 c0, c1;
#pragma unroll
      for (int e = 0; e < 4; ++e) {
        c0[e] = (bf16_t)na0[e]; c0[e + 4] = (bf16_t)na1[e];
        c1[e] = (bf16_t)na2[e]; c1[e + 4] = (bf16_t)na3[e];
      }
      *(bf16x8*)&As[cur ^ 1][trow * ALD + tcol] = c0;
      *(bf16x8*)&As[cur ^ 1][trow * ALD + tcol + 8] = c1;
    }

    // ---- single end-of-step sync: all stage writes landed, all reads done ----
    asm volatile("s_waitcnt vmcnt(0) lgkmcnt(0)" ::: "memory");
    __builtin_amdgcn_sched_barrier(0);
    __builtin_amdgcn_s_barrier();
    cur ^= 1;
  }

  // ---- epilogue: bias + store ----
#pragma unroll
  for (int i = 0; i < 2; ++i)
#pragma unroll
    for (int j = 0; j < 2; ++j) {
      const int col = bn + wc + j * 16 + lm;
      const float bvv = bias[col];
#pragma unroll
      for (int r = 0; r < 4; ++r) {
        const int row = bm + wr + i * 16 + cr4 + r;
        C[(size_t)row * N + col] = (CT)(acc[i][j][r] + bvv);
      }
    }
}

// ---------------- per-(token,head) channel attention ----------------
__global__ __launch_bounds__(256) void attn_kernel(
    const bf16_t* __restrict__ q, const bf16_t* __restrict__ k,
    const bf16_t* __restrict__ v, bf16_t* __restrict__ ctx) {
  __shared__ float kv[4][64][2];
  const int wv = threadIdx.x >> 6, lane = threadIdx.x & 63;
  const int pair = blockIdx.x * 4 + wv;          // t*16 + h
  const size_t base = (size_t)pair * 64;
  float qd = (float)q[base + lane];
  float kd = (float)k[base + lane];
  float vd = (float)v[base + lane];
  kv[wv][lane][0] = kd;
  kv[wv][lane][1] = vd;
  __syncthreads();

  float kmax = kd, kmin = kd;
#pragma unroll
  for (int off = 32; off; off >>= 1) {
    kmax = fmaxf(kmax, __shfl_xor(kmax, off));
    kmin = fminf(kmin, __shfl_xor(kmin, off));
  }
  const float sc = 0.125f * 1.44269504088896341f;  // (1/sqrt(64)) * log2(e)
  float a = (float)qd * sc;
  float m = fmaxf(a * kmax, a * kmin);
  float sum = 0.f, accv = 0.f;
#pragma unroll 8
  for (int j = 0; j < 64; ++j) {
    float kj = kv[wv][j][0];
    float vj = kv[wv][j][1];
    float e = exp2f(fmaf(a, kj, -m));
    sum += e;
    accv = fmaf(e, vj, accv);
  }
  ctx[base + lane] = (bf16_t)(accv * __builtin_amdgcn_rcpf(sum));
}

// ---------------- launch ----------------
extern "C" void kernel_launch(void* const* d_in, const int* in_sizes, int n_in,
                              void* d_out, int out_size, void* d_ws, size_t ws_size,
                              hipStream_t stream) {
  const float* query = (const float*)d_in[0];
  const float* key   = (const float*)d_in[1];
  const float* value = (const float*)d_in[2];
  const float* Wq = (const float*)d_in[3];
  const float* bq = (const float*)d_in[4];
  const float* Wk = (const float*)d_in[5];
  const float* bk = (const float*)d_in[6];
  const float* Wv = (const float*)d_in[7];
  const float* bv = (const float*)d_in[8];
  const float* Wo = (const float*)d_in[9];
  const float* bo = (const float*)d_in[10];
  float* out = (float*)d_out;

  const size_t XE = (size_t)TOK * DMODEL;
  const size_t WE = (size_t)DMODEL * DMODEL;

  char* ws = (char*)d_ws;
  size_t off = 0;
  bf16_t* wb[4];
  for (int i = 0; i < 4; ++i) { wb[i] = (bf16_t*)(ws + off); off += WE * 2; }
  bf16_t* pb[3];   // projected q,k,v bf16
  for (int i = 0; i < 3; ++i) { pb[i] = (bf16_t*)(ws + off); off += XE * 2; }
  bf16_t* ctxb = (bf16_t*)(ws + off); off += XE * 2;

  // 1) convert weights to bf16
  CvtArgs ca;
  ca.src[0] = Wq; ca.src[1] = Wk; ca.src[2] = Wv; ca.src[3] = Wo;
  ca.dst[0] = wb[0]; ca.dst[1] = wb[1]; ca.dst[2] = wb[2]; ca.dst[3] = wb[3];
  cvt_kernel<<<dim3((unsigned)(WE / (256 * 8)), 4), 256, 0, stream>>>(ca);

  // 2) QKV projection (batched z, fp32 A converted in staging): 32x16x3 = 1536 blocks
  GArgs g1;
  g1.A[0] = query; g1.A[1] = key; g1.A[2] = value;
  g1.W[0] = wb[0]; g1.W[1] = wb[1]; g1.W[2] = wb[2];
  g1.bias[0] = bq; g1.bias[1] = bk; g1.bias[2] = bv;
  g1.C[0] = pb[0]; g1.C[1] = pb[1]; g1.C[2] = pb[2];
  gemm3<true, bf16_t><<<dim3(TOK / 64, DMODEL / 64, 3), 256, 0, stream>>>(g1, DMODEL);

  // 3) per-(token,head) channel attention
  attn_kernel<<<dim3(TOK * NHEAD / 4), 256, 0, stream>>>(pb[0], pb[1], pb[2], ctxb);

  // 4) output projection -> fp32 out (bf16 A via gload_lds): 32x16 = 512 blocks
  GArgs g2;
  g2.A[0] = ctxb; g2.W[0] = wb[3]; g2.bias[0] = bo; g2.C[0] = out;
  g2.A[1] = ctxb; g2.W[1] = wb[3]; g2.bias[1] = bo; g2.C[1] = out;
  g2.A[2] = ctxb; g2.W[2] = wb[3]; g2.bias[2] = bo; g2.C[2] = out;
  gemm3<false, float><<<dim3(TOK / 64, DMODEL / 64, 1), 256, 0, stream>>>(g2, DMODEL);
}

// Round 5
// 79.713 us; speedup vs baseline: 1.2663x; 1.2663x over previous
//
#include <hip/hip_runtime.h>
#include <hip/hip_bf16.h>
#include <stdint.h>
#include <stddef.h>

typedef __bf16 bf16_t;
typedef __attribute__((ext_vector_type(8))) __bf16 bf16x8;
typedef __attribute__((ext_vector_type(4))) float f32x4;

#define TOK 2048      // N*M tokens
#define DMODEL 1024
#define NHEAD 16

__device__ __forceinline__ void gload_lds16(const void* g, void* l) {
  __builtin_amdgcn_global_load_lds(
      (const __attribute__((address_space(1))) void*)g,
      (__attribute__((address_space(3))) void*)l, 16, 0, 0);
}

// ---------------- fp32 -> bf16 batched convert (X + weights) ----------------
struct CvtArgs {
  const float* src[7];
  bf16_t* dst[7];
  int n[7];
};

__global__ __launch_bounds__(256) void cvt_kernel(CvtArgs a) {
  int arr = blockIdx.y;
  int n = a.n[arr];
  int i = (blockIdx.x * 256 + threadIdx.x) * 8;
  if (i >= n) return;
  const float* s = a.src[arr];
  bf16_t* d = a.dst[arr];
  f32x4 x0 = *(const f32x4*)(s + i);
  f32x4 x1 = *(const f32x4*)(s + i + 4);
  bf16x8 o;
  o[0] = (bf16_t)x0[0]; o[1] = (bf16_t)x0[1]; o[2] = (bf16_t)x0[2]; o[3] = (bf16_t)x0[3];
  o[4] = (bf16_t)x1[0]; o[5] = (bf16_t)x1[1]; o[6] = (bf16_t)x1[2]; o[7] = (bf16_t)x1[3];
  *(bf16x8*)(d + i) = o;
}

// =============== 64x64-tile GEMM, BK=64, 3-buffer counted-vmcnt pipeline ===============
// C[row][col] = sum_k A[row][k] * W[col][k] + bias[col]   (M=2048, N=K=1024)
// Both A and W staged via global_load_lds (16B) into linear LDS with XOR chunk
// swizzle applied on BOTH the per-lane global source and the ds_read offsets.
struct GArgs {
  const bf16_t* A[3];
  const bf16_t* W[3];
  const float* bias[3];
  void* C[3];
};

template <typename CT>
__global__ __launch_bounds__(256, 3) void gemm3(GArgs g) {
  constexpr int K = DMODEL, N = DMODEL;
  // XCD-locality decode: xcd owns a contiguous 4-strip of bm x all bn.
  // (hw dispatches blockIdx.x round-robin across 8 XCDs)
  const int i = blockIdx.x;
  const int xcd = i & 7, slot = i >> 3;
  const int z = slot >> 6;             // 0..2 (qkv) or always 0 (out-proj)
  const int s = slot & 63;
  const int bm = (xcd * 4 + (s >> 4)) * 64;
  const int bn = (s & 15) * 64;

  const bf16_t* __restrict__ A = g.A[z];
  const bf16_t* __restrict__ W = g.W[z];
  const float* __restrict__ bias = g.bias[z];
  CT* __restrict__ C = (CT*)g.C[z];

  __shared__ alignas(16) bf16_t As[3][64 * 64];
  __shared__ alignas(16) bf16_t Bs[3][64 * 64];

  const int tid = threadIdx.x;
  const int wv = tid >> 6, lane = tid & 63;
  const int wr = (wv >> 1) * 32, wc = (wv & 1) * 32;
  const int lm = lane & 15, lch = lane >> 4;
  const int cr4 = (lane >> 4) * 4;

  // staging coords: wave covers rows [wv*8, wv*8+8) (+32 for 2nd instr);
  // lane r=lane>>3 (local row), c=lane&7 (chunk); source chunk pre-XORed
  const int srow = wv * 8 + (lane >> 3);
  const int sc = (lane & 7) ^ (lane >> 3);
  const bf16_t* Abase = A + (size_t)(bm + srow) * K + sc * 8;
  const bf16_t* Wbase = W + (size_t)(bn + srow) * K + sc * 8;
  const int ldsoff0 = (wv * 8) * 64;
  const int ldsoff1 = (wv * 8 + 32) * 64;

  f32x4 acc[2][2] = {};
  constexpr int nt = K / 64;   // 16

  // ---- prologue: stage tiles 0 and 1 (8 loads outstanding) ----
#pragma unroll
  for (int t0 = 0; t0 < 2; ++t0) {
    const int b = t0;
    gload_lds16(Abase + t0 * 64, &As[b][ldsoff0]);
    gload_lds16(Abase + t0 * 64 + (size_t)32 * K, &As[b][ldsoff1]);
    gload_lds16(Wbase + t0 * 64, &Bs[b][ldsoff0]);
    gload_lds16(Wbase + t0 * 64 + (size_t)32 * K, &Bs[b][ldsoff1]);
  }

  for (int t = 0; t < nt; ++t) {
    // wait for tile t's 4 loads (leave tile t+1's 4 in flight), then sync
    if (t + 1 < nt) {
      asm volatile("s_waitcnt vmcnt(4) lgkmcnt(0)" ::: "memory");
    } else {
      asm volatile("s_waitcnt vmcnt(0) lgkmcnt(0)" ::: "memory");
    }
    __builtin_amdgcn_sched_barrier(0);
    __builtin_amdgcn_s_barrier();
    __builtin_amdgcn_sched_barrier(0);   // pin stage AFTER barrier (buf-recycle race)

    // issue stage of tile t+2 into buf (t+2)%3 (freed at the barrier above)
    if (t + 2 < nt) {
      const int b2 = (t + 2) % 3;
      gload_lds16(Abase + (t + 2) * 64, &As[b2][ldsoff0]);
      gload_lds16(Abase + (t + 2) * 64 + (size_t)32 * K, &As[b2][ldsoff1]);
      gload_lds16(Wbase + (t + 2) * 64, &Bs[b2][ldsoff0]);
      gload_lds16(Wbase + (t + 2) * 64 + (size_t)32 * K, &Bs[b2][ldsoff1]);
    }

    // ds_read fragments of tile t (XOR-swizzled chunks)
    const int b = t % 3;
    bf16x8 fa[2][2], fb[2][2];
#pragma unroll
    for (int kk = 0; kk < 2; ++kk)
#pragma unroll
      for (int ii = 0; ii < 2; ++ii) {
        const int ra = wr + ii * 16 + lm;
        fa[kk][ii] = *(const bf16x8*)&As[b][ra * 64 + (((kk * 4 + lch) ^ (ra & 7)) * 8)];
        const int rb = wc + ii * 16 + lm;
        fb[kk][ii] = *(const bf16x8*)&Bs[b][rb * 64 + (((kk * 4 + lch) ^ (rb & 7)) * 8)];
      }

#pragma unroll
    for (int kk = 0; kk < 2; ++kk)
#pragma unroll
      for (int ii = 0; ii < 2; ++ii)
#pragma unroll
        for (int jj = 0; jj < 2; ++jj)
          acc[ii][jj] = __builtin_amdgcn_mfma_f32_16x16x32_bf16(fa[kk][ii], fb[kk][jj], acc[ii][jj], 0, 0, 0);
  }

  // ---- epilogue: bias + store ----
#pragma unroll
  for (int ii = 0; ii < 2; ++ii)
#pragma unroll
    for (int jj = 0; jj < 2; ++jj) {
      const int col = bn + wc + jj * 16 + lm;
      const float bvv = bias[col];
#pragma unroll
      for (int r = 0; r < 4; ++r) {
        const int row = bm + wr + ii * 16 + cr4 + r;
        C[(size_t)row * N + col] = (CT)(acc[ii][jj][r] + bvv);
      }
    }
}

// ---------------- per-(token,head) channel attention ----------------
__global__ __launch_bounds__(256) void attn_kernel(
    const bf16_t* __restrict__ q, const bf16_t* __restrict__ k,
    const bf16_t* __restrict__ v, bf16_t* __restrict__ ctx) {
  __shared__ float kv[4][64][2];
  const int wv = threadIdx.x >> 6, lane = threadIdx.x & 63;
  const int pair = blockIdx.x * 4 + wv;          // t*16 + h
  const size_t base = (size_t)pair * 64;
  float qd = (float)q[base + lane];
  float kd = (float)k[base + lane];
  float vd = (float)v[base + lane];
  kv[wv][lane][0] = kd;
  kv[wv][lane][1] = vd;
  __syncthreads();

  float kmax = kd, kmin = kd;
#pragma unroll
  for (int off = 32; off; off >>= 1) {
    kmax = fmaxf(kmax, __shfl_xor(kmax, off));
    kmin = fminf(kmin, __shfl_xor(kmin, off));
  }
  const float sc = 0.125f * 1.44269504088896341f;  // (1/sqrt(64)) * log2(e)
  float a = (float)qd * sc;
  float m = fmaxf(a * kmax, a * kmin);
  float sum = 0.f, accv = 0.f;
#pragma unroll 8
  for (int j = 0; j < 64; ++j) {
    float kj = kv[wv][j][0];
    float vj = kv[wv][j][1];
    float e = exp2f(fmaf(a, kj, -m));
    sum += e;
    accv = fmaf(e, vj, accv);
  }
  ctx[base + lane] = (bf16_t)(accv * __builtin_amdgcn_rcpf(sum));
}

// ---------------- launch ----------------
extern "C" void kernel_launch(void* const* d_in, const int* in_sizes, int n_in,
                              void* d_out, int out_size, void* d_ws, size_t ws_size,
                              hipStream_t stream) {
  const float* query = (const float*)d_in[0];
  const float* key   = (const float*)d_in[1];
  const float* value = (const float*)d_in[2];
  const float* Wq = (const float*)d_in[3];
  const float* bq = (const float*)d_in[4];
  const float* Wk = (const float*)d_in[5];
  const float* bk = (const float*)d_in[6];
  const float* Wv = (const float*)d_in[7];
  const float* bv = (const float*)d_in[8];
  const float* Wo = (const float*)d_in[9];
  const float* bo = (const float*)d_in[10];
  float* out = (float*)d_out;

  const size_t XE = (size_t)TOK * DMODEL;
  const size_t WE = (size_t)DMODEL * DMODEL;

  char* ws = (char*)d_ws;
  size_t off = 0;
  bf16_t* xb[3];
  for (int i = 0; i < 3; ++i) { xb[i] = (bf16_t*)(ws + off); off += XE * 2; }
  bf16_t* wb[4];
  for (int i = 0; i < 4; ++i) { wb[i] = (bf16_t*)(ws + off); off += WE * 2; }
  bf16_t* pb[3];   // projected q,k,v bf16
  for (int i = 0; i < 3; ++i) { pb[i] = (bf16_t*)(ws + off); off += XE * 2; }
  bf16_t* ctxb = (bf16_t*)(ws + off); off += XE * 2;

  // 1) convert X and weights to bf16
  CvtArgs ca;
  ca.src[0] = query; ca.src[1] = key; ca.src[2] = value;
  ca.src[3] = Wq; ca.src[4] = Wk; ca.src[5] = Wv; ca.src[6] = Wo;
  ca.dst[0] = xb[0]; ca.dst[1] = xb[1]; ca.dst[2] = xb[2];
  ca.dst[3] = wb[0]; ca.dst[4] = wb[1]; ca.dst[5] = wb[2]; ca.dst[6] = wb[3];
  ca.n[0] = ca.n[1] = ca.n[2] = (int)XE;
  ca.n[3] = ca.n[4] = ca.n[5] = ca.n[6] = (int)WE;
  cvt_kernel<<<dim3((unsigned)(XE / (256 * 8)), 7), 256, 0, stream>>>(ca);

  // 2) QKV projection: 1536 blocks (xcd-local bm strips)
  GArgs g1;
  g1.A[0] = xb[0]; g1.A[1] = xb[1]; g1.A[2] = xb[2];
  g1.W[0] = wb[0]; g1.W[1] = wb[1]; g1.W[2] = wb[2];
  g1.bias[0] = bq; g1.bias[1] = bk; g1.bias[2] = bv;
  g1.C[0] = pb[0]; g1.C[1] = pb[1]; g1.C[2] = pb[2];
  gemm3<bf16_t><<<dim3(1536), 256, 0, stream>>>(g1);

  // 3) per-(token,head) channel attention
  attn_kernel<<<dim3(TOK * NHEAD / 4), 256, 0, stream>>>(pb[0], pb[1], pb[2], ctxb);

  // 4) output projection -> fp32 out: 512 blocks
  GArgs g2;
  g2.A[0] = ctxb; g2.W[0] = wb[3]; g2.bias[0] = bo; g2.C[0] = out;
  g2.A[1] = ctxb; g2.W[1] = wb[3]; g2.bias[1] = bo; g2.C[1] = out;
  g2.A[2] = ctxb; g2.W[2] = wb[3]; g2.bias[2] = bo; g2.C[2] = out;
  gemm3<float><<<dim3(512), 256, 0, stream>>>(g2);
}